// Round 8
// baseline (374.347 us; speedup 1.0000x reference)
//
#include <hip/hip_runtime.h>
#include <hip/hip_bf16.h>
#include <cstdint>
#include <cstddef>

using u16 = unsigned short;
typedef __bf16 bf16x8 __attribute__((ext_vector_type(8)));
typedef float f32x4 __attribute__((ext_vector_type(4)));
typedef float f32x16 __attribute__((ext_vector_type(16)));
typedef u16 u16x4 __attribute__((ext_vector_type(4)));
typedef u16 u16x8 __attribute__((ext_vector_type(8)));
typedef uint32_t u32x4 __attribute__((ext_vector_type(4)));

__device__ __forceinline__ u16 f2bf(float f) {
  uint32_t u = __builtin_bit_cast(uint32_t, f);
  u += 0x7FFFu + ((u >> 16) & 1u);   // RNE
  return (u16)(u >> 16);
}

__device__ __forceinline__ void gld_lds16(const void* g, void* l) {
  __builtin_amdgcn_global_load_lds(
      (const __attribute__((address_space(1))) unsigned int*)g,
      (__attribute__((address_space(3))) unsigned int*)l, 16, 0, 0);
}

#define MFMA16(a, b, c) __builtin_amdgcn_mfma_f32_16x16x32_bf16((a), (b), (c), 0, 0, 0)
#define MFMA32(a, b, c) __builtin_amdgcn_mfma_f32_32x32x16_bf16((a), (b), (c), 0, 0, 0)

__device__ __forceinline__ uint32_t pkbf(float a, float b) {
  uint32_t d;
  asm("v_cvt_pk_bf16_f32 %0, %1, %2" : "=v"(d) : "v"(a), "v"(b));
  return d;
}
__device__ __forceinline__ void swap32(uint32_t& a, uint32_t& b) {
  asm volatile("v_permlane32_swap_b32 %0, %1" : "+v"(a), "+v"(b));
}

// ---------------- fp32 -> bf16 converts ----------------
__global__ void cvt_kernel(const float* __restrict__ in, u16* __restrict__ out, int n4) {
  int i = blockIdx.x * blockDim.x + threadIdx.x;
  int stride = gridDim.x * blockDim.x;
  for (; i < n4; i += stride) {
    float4 v = reinterpret_cast<const float4*>(in)[i];
    u16x4 o;
    o[0] = f2bf(v.x); o[1] = f2bf(v.y); o[2] = f2bf(v.z); o[3] = f2bf(v.w);
    reinterpret_cast<u16x4*>(out)[i] = o;
  }
}

__global__ void cvt4_kernel(const float* __restrict__ x, const float* __restrict__ Wq,
                            const float* __restrict__ Wk, const float* __restrict__ Wv,
                            u16* __restrict__ xb, u16* __restrict__ Wc) {
  int i = blockIdx.x * blockDim.x + threadIdx.x;
  int stride = gridDim.x * blockDim.x;
  for (; i < 3670016; i += stride) {
    const float* src; u16* dst; int off;
    if (i < 2097152)      { src = x;  dst = xb;            off = i; }
    else if (i < 3145728) { src = Wq; dst = Wc;            off = i - 2097152; }
    else if (i < 3407872) { src = Wk; dst = Wc + 4194304;  off = i - 3145728; }
    else                  { src = Wv; dst = Wc + 5242880;  off = i - 3407872; }
    float4 v = reinterpret_cast<const float4*>(src)[off];
    u16x4 o;
    o[0] = f2bf(v.x); o[1] = f2bf(v.y); o[2] = f2bf(v.z); o[3] = f2bf(v.w);
    reinterpret_cast<u16x4*>(dst)[off] = o;
  }
}

// ---------------- bf16 GEMM (unchanged from R7) ----------------
template <bool OUT_BF16>
__global__ __launch_bounds__(256) void gemm_bt(const u16* __restrict__ A,
                                               const u16* __restrict__ B,
                                               void* __restrict__ Cv,
                                               int M, int N, int K) {
  __shared__ __align__(16) u16 Ash[3][128 * 32];
  __shared__ __align__(16) u16 Bsh[3][128 * 32];
  const int tid = threadIdx.x;
  const int w = tid >> 6, lane = tid & 63, ql = lane & 15, g = lane >> 4;
  const int wr = w >> 1, wc = w & 1;
  const int m0 = blockIdx.y * 128, n0 = blockIdx.x * 128;
  const int srow = w * 16 + (lane >> 2);
  const int sk = (lane & 3) * 8;
  const u16* Abase = A + (size_t)(m0 + srow) * K + sk;
  const u16* Bbase = B + (size_t)(n0 + srow) * K + sk;

  f32x4 acc[4][4];
#pragma unroll
  for (int i = 0; i < 4; i++)
#pragma unroll
    for (int j = 0; j < 4; j++) acc[i][j] = f32x4{0.f, 0.f, 0.f, 0.f};

  auto stage = [&](int bi, int tile) {
    const int kt = tile * 32;
    gld_lds16(Abase + kt,                  &Ash[bi][w * 512]);
    gld_lds16(Abase + (size_t)64 * K + kt, &Ash[bi][2048 + w * 512]);
    gld_lds16(Bbase + kt,                  &Bsh[bi][w * 512]);
    gld_lds16(Bbase + (size_t)64 * K + kt, &Bsh[bi][2048 + w * 512]);
  };

  const int nt = K >> 5;
  stage(0, 0);
  stage(1, 1);
  asm volatile("s_waitcnt vmcnt(4)" ::: "memory");
  __builtin_amdgcn_sched_barrier(0);
  __builtin_amdgcn_s_barrier();
  __builtin_amdgcn_sched_barrier(0);

  int cur = 0;
  for (int t = 0; t < nt; ++t) {
    if (t + 2 < nt) {
      int stg = cur + 2; if (stg >= 3) stg -= 3;
      stage(stg, t + 2);
    }
    bf16x8 af[4], bfr[4];
#pragma unroll
    for (int i = 0; i < 4; i++)
      af[i] = *reinterpret_cast<const bf16x8*>(&Ash[cur][(wr * 64 + i * 16 + ql) * 32 + g * 8]);
#pragma unroll
    for (int j = 0; j < 4; j++)
      bfr[j] = *reinterpret_cast<const bf16x8*>(&Bsh[cur][(wc * 64 + j * 16 + ql) * 32 + g * 8]);
    __builtin_amdgcn_s_setprio(1);
#pragma unroll
    for (int i = 0; i < 4; i++)
#pragma unroll
      for (int j = 0; j < 4; j++)
        acc[i][j] = MFMA16(af[i], bfr[j], acc[i][j]);
    __builtin_amdgcn_s_setprio(0);
    if (t + 1 < nt) {
      if (t + 2 < nt) {
        asm volatile("s_waitcnt vmcnt(4)" ::: "memory");
      } else {
        asm volatile("s_waitcnt vmcnt(0)" ::: "memory");
      }
      __builtin_amdgcn_sched_barrier(0);
      __builtin_amdgcn_s_barrier();
      __builtin_amdgcn_sched_barrier(0);
    }
    cur = (cur == 2) ? 0 : cur + 1;
  }

#pragma unroll
  for (int i = 0; i < 4; i++)
#pragma unroll
    for (int j = 0; j < 4; j++)
#pragma unroll
      for (int r = 0; r < 4; r++) {
        const int row = m0 + wr * 64 + i * 16 + g * 4 + r;
        const int col = n0 + wc * 64 + j * 16 + ql;
        if constexpr (OUT_BF16)
          ((u16*)Cv)[(size_t)row * N + col] = f2bf(acc[i][j][r]);
        else
          ((float*)Cv)[(size_t)row * N + col] = acc[i][j][r];
      }
}

// ---------------- flash attention v6: 64 q/wave, shared-fragment MFMA ----------------
// Each wave owns TWO 32-q columns; every KFRAG/VFRAG LDS read feeds 2 MFMAs ->
// frag-read bytes per FLOP halved. KVBLK=32 (sc regs), no deferred-PV / no lacc
// (R7: both ~neutral), scalar-l, defer-max kept, T14 V split kept.
// Block = 4 waves x 64q = 256 q-tile; grid 256 (1/CU), XCD-swizzled; LDS 34.8KB.
__global__ __launch_bounds__(256, 2) void attn_kernel(const u16* __restrict__ QKV,
                                                      u16* __restrict__ O) {
  // SH partition (u16): Kb = [0,8192) : 2 bufs x [32s][128k], slot16 ^= (s&7)
  //                     Vb = [8192,16384): 2 bufs x [128d][32s], col8 ^= key(d)
  //                     epilogue: SH + w*4352 (32q x 136)
  __shared__ __align__(16) u16 SH[17408];
  const int tid = threadIdx.x, w = tid >> 6, lane = tid & 63;
  const int lq = lane & 31, hi = lane >> 5;
  // XCD swizzle: class = bid&7 -> (b,hkv); u = bid>>3 -> (h-in-group, qt)
  const int bid = blockIdx.x;
  const int cls = bid & 7, uu = bid >> 3;
  const int b = cls >> 2, hkv = cls & 3;
  const int h = hkv * 4 + (uu >> 3), qt = uu & 7;
  const size_t rowb = (size_t)b * 2048;
  const int qbase = qt * 256 + w * 64;

  const u16* Kg = QKV + 2048 + hkv * 128;
  const u16* Vg = QKV + 2560 + hkv * 128;

  // Q frags for both q-columns (held all kernel): B[col=q=lq][k=s5*16+hi*8+j]
  bf16x8 bq0[8], bq1[8];
  {
    const u16* qp0 = QKV + (rowb + qbase + lq) * 3072 + h * 128 + hi * 8;
    const u16* qp1 = qp0 + (size_t)32 * 3072;
#pragma unroll
    for (int s5 = 0; s5 < 8; s5++) {
      bq0[s5] = *reinterpret_cast<const bf16x8*>(qp0 + s5 * 16);
      bq1[s5] = *reinterpret_cast<const bf16x8*>(qp1 + s5 * 16);
    }
  }

  const int dg = tid & 7, sl = tid >> 3;   // V stage: s=sl (0..31), d-group dg
  const int ks = tid >> 4, kslot = tid & 15;  // K stage mapping

  f32x16 oa0[4], oa1[4];
#pragma unroll
  for (int dt = 0; dt < 4; dt++)
#pragma unroll
    for (int i = 0; i < 16; i++) { oa0[dt][i] = 0.f; oa1[dt][i] = 0.f; }
  float m0 = -INFINITY, m1 = -INFINITY, l0 = 0.f, l1 = 0.f;
  const float CEXP = 0.08838834764831845f * 1.4426950408889634f;  // scale*log2e

  auto stageK = [&](int pb, int sbase) {
#pragma unroll
    for (int p = 0; p < 2; p++) {
      const int s = p * 16 + ks;
      gld_lds16(Kg + (rowb + sbase + s) * 3072 + ((kslot ^ (s & 7)) << 3),
                &SH[pb * 4096 + p * 2048 + w * 512]);
    }
  };
  auto writeV = [&](int pb, const u16x8& a0, const u16x8& a1) {
#pragma unroll
    for (int hf = 0; hf < 2; hf++) {
      const u16x8 v = hf ? a1 : a0;
#pragma unroll
      for (int j = 0; j < 8; j++) {
        const int d = dg * 16 + hf * 8 + j;
        const int key = ((d >> 1) ^ (d >> 4)) & 3;
        SH[8192 + pb * 4096 + d * 32 + (sl ^ (key << 3))] = v[j];
      }
    }
  };

#define KFRAG(PB, S5) \
  (*reinterpret_cast<const bf16x8*>(&SH[(PB)*4096 + lq * 128 + ((((S5)*2 + hi) ^ (lq & 7)) << 3)]))
#define VFRAG(PB, DT, SS) \
  (*reinterpret_cast<const bf16x8*>(&SH[8192 + (PB)*4096 + ((DT)*32 + lq) * 32 + \
      (((SS)*16 + hi * 8) ^ ((((((DT)*32 + lq) >> 1) ^ (((DT)*32 + lq) >> 4)) & 3) << 3))]))

  // ---- prologue: tile 0 ----
  u16x8 va, vb2;
  {
    const u16* vp = Vg + (rowb + sl) * 3072 + dg * 16;
    va  = *reinterpret_cast<const u16x8*>(vp);
    vb2 = *reinterpret_cast<const u16x8*>(vp + 8);
  }
  stageK(0, 0);
  writeV(0, va, vb2);
  __syncthreads();

#pragma unroll 1
  for (int sb = 0; sb < 64; sb++) {
    const int pb = sb & 1;
    // T14: issue next-tile loads first
    if (sb < 63) {
      const u16* vp = Vg + (rowb + (sb + 1) * 32 + sl) * 3072 + dg * 16;
      va  = *reinterpret_cast<const u16x8*>(vp);
      vb2 = *reinterpret_cast<const u16x8*>(vp + 8);
      stageK(pb ^ 1, (sb + 1) * 32);
    }

    // ---- S^T = K @ Q^T: shared KFRAG feeds both q-columns ----
    f32x16 sc0, sc1;
#pragma unroll
    for (int i = 0; i < 16; i++) { sc0[i] = 0.f; sc1[i] = 0.f; }
    __builtin_amdgcn_s_setprio(1);
#pragma unroll
    for (int s5 = 0; s5 < 8; s5++) {
      bf16x8 kf = KFRAG(pb, s5);
      sc0 = MFMA32(kf, bq0[s5], sc0);
      sc1 = MFMA32(kf, bq1[s5], sc1);
    }
    __builtin_amdgcn_s_setprio(0);

    bf16x8 pf00, pf01, pf10, pf11;

    // ---- softmax qc0 (in-lane max, defer-max, exp in place, scalar l, pack) ----
    {
      float u[8];
#pragma unroll
      for (int i = 0; i < 8; i++) u[i] = fmaxf(sc0[i], sc0[i + 8]);
#pragma unroll
      for (int i = 0; i < 4; i++) u[i] = fmaxf(u[i], u[i + 4]);
      float mx = fmaxf(fmaxf(u[0], u[1]), fmaxf(u[2], u[3]));
      mx = fmaxf(mx, __shfl_xor(mx, 32));
      if (__any((mx - m0) * CEXP > 8.0f)) {
        const float mn = fmaxf(m0, mx);
        const float corr = exp2f((m0 - mn) * CEXP);
        l0 *= corr;
#pragma unroll
        for (int dt = 0; dt < 4; dt++)
#pragma unroll
          for (int i = 0; i < 16; i++) oa0[dt][i] *= corr;
        m0 = mn;
      }
      const float mC = m0 * CEXP;
#pragma unroll
      for (int i = 0; i < 16; i++) sc0[i] = exp2f(fmaf(sc0[i], CEXP, -mC));
      float s[8];
#pragma unroll
      for (int i = 0; i < 8; i++) s[i] = sc0[i] + sc0[i + 8];
#pragma unroll
      for (int i = 0; i < 4; i++) s[i] = s[i] + s[i + 4];
      float ps = (s[0] + s[1]) + (s[2] + s[3]);
      ps += __shfl_xor(ps, 32);
      l0 += ps;
      uint32_t a, bw; u32x4 f;
      a = pkbf(sc0[0], sc0[1]);   bw = pkbf(sc0[4], sc0[5]);   swap32(a, bw);
      f[0] = a; f[2] = bw;
      a = pkbf(sc0[2], sc0[3]);   bw = pkbf(sc0[6], sc0[7]);   swap32(a, bw);
      f[1] = a; f[3] = bw;
      pf00 = __builtin_bit_cast(bf16x8, f);
      a = pkbf(sc0[8], sc0[9]);   bw = pkbf(sc0[12], sc0[13]); swap32(a, bw);
      f[0] = a; f[2] = bw;
      a = pkbf(sc0[10], sc0[11]); bw = pkbf(sc0[14], sc0[15]); swap32(a, bw);
      f[1] = a; f[3] = bw;
      pf01 = __builtin_bit_cast(bf16x8, f);
    }
    // ---- softmax qc1 ----
    {
      float u[8];
#pragma unroll
      for (int i = 0; i < 8; i++) u[i] = fmaxf(sc1[i], sc1[i + 8]);
#pragma unroll
      for (int i = 0; i < 4; i++) u[i] = fmaxf(u[i], u[i + 4]);
      float mx = fmaxf(fmaxf(u[0], u[1]), fmaxf(u[2], u[3]));
      mx = fmaxf(mx, __shfl_xor(mx, 32));
      if (__any((mx - m1) * CEXP > 8.0f)) {
        const float mn = fmaxf(m1, mx);
        const float corr = exp2f((m1 - mn) * CEXP);
        l1 *= corr;
#pragma unroll
        for (int dt = 0; dt < 4; dt++)
#pragma unroll
          for (int i = 0; i < 16; i++) oa1[dt][i] *= corr;
        m1 = mn;
      }
      const float mC = m1 * CEXP;
#pragma unroll
      for (int i = 0; i < 16; i++) sc1[i] = exp2f(fmaf(sc1[i], CEXP, -mC));
      float s[8];
#pragma unroll
      for (int i = 0; i < 8; i++) s[i] = sc1[i] + sc1[i + 8];
#pragma unroll
      for (int i = 0; i < 4; i++) s[i] = s[i] + s[i + 4];
      float ps = (s[0] + s[1]) + (s[2] + s[3]);
      ps += __shfl_xor(ps, 32);
      l1 += ps;
      uint32_t a, bw; u32x4 f;
      a = pkbf(sc1[0], sc1[1]);   bw = pkbf(sc1[4], sc1[5]);   swap32(a, bw);
      f[0] = a; f[2] = bw;
      a = pkbf(sc1[2], sc1[3]);   bw = pkbf(sc1[6], sc1[7]);   swap32(a, bw);
      f[1] = a; f[3] = bw;
      pf10 = __builtin_bit_cast(bf16x8, f);
      a = pkbf(sc1[8], sc1[9]);   bw = pkbf(sc1[12], sc1[13]); swap32(a, bw);
      f[0] = a; f[2] = bw;
      a = pkbf(sc1[10], sc1[11]); bw = pkbf(sc1[14], sc1[15]); swap32(a, bw);
      f[1] = a; f[3] = bw;
      pf11 = __builtin_bit_cast(bf16x8, f);
    }

    // ---- O^T += V^T @ P^T: shared VFRAG feeds both q-columns ----
    __builtin_amdgcn_s_setprio(1);
#pragma unroll
    for (int dt = 0; dt < 4; dt++) {
      bf16x8 vf0 = VFRAG(pb, dt, 0);
      oa0[dt] = MFMA32(vf0, pf00, oa0[dt]);
      oa1[dt] = MFMA32(vf0, pf10, oa1[dt]);
      bf16x8 vf1 = VFRAG(pb, dt, 1);
      oa0[dt] = MFMA32(vf1, pf01, oa0[dt]);
      oa1[dt] = MFMA32(vf1, pf11, oa1[dt]);
    }
    __builtin_amdgcn_s_setprio(0);

    if (sb < 63) writeV(pb ^ 1, va, vb2);  // write-late
    __syncthreads();
  }

  // ---- epilogue: two statically-indexed passes through per-wave LDS region ----
  u16* ob = SH + w * 4352;
  const int orow = lane >> 1, och = (lane & 1) * 64;
  {
    const float rl = 1.0f / l0;
#pragma unroll
    for (int dt = 0; dt < 4; dt++)
#pragma unroll
      for (int rq = 0; rq < 4; rq++) {
        u16x4 pv;
#pragma unroll
        for (int k = 0; k < 4; k++) pv[k] = f2bf(oa0[dt][rq * 4 + k] * rl);
        *reinterpret_cast<u16x4*>(&ob[lq * 136 + dt * 32 + rq * 8 + hi * 4]) = pv;
      }
    u16* og = O + (rowb + qbase + orow) * 2048 + h * 128 + och;
#pragma unroll
    for (int t = 0; t < 8; t++) {
      u16x8 v = *reinterpret_cast<const u16x8*>(&ob[orow * 136 + och + t * 8]);
      *reinterpret_cast<u16x8*>(og + t * 8) = v;
    }
  }
  {
    const float rl = 1.0f / l1;
#pragma unroll
    for (int dt = 0; dt < 4; dt++)
#pragma unroll
      for (int rq = 0; rq < 4; rq++) {
        u16x4 pv;
#pragma unroll
        for (int k = 0; k < 4; k++) pv[k] = f2bf(oa1[dt][rq * 4 + k] * rl);
        *reinterpret_cast<u16x4*>(&ob[lq * 136 + dt * 32 + rq * 8 + hi * 4]) = pv;
      }
    u16* og = O + (rowb + qbase + 32 + orow) * 2048 + h * 128 + och;
#pragma unroll
    for (int t = 0; t < 8; t++) {
      u16x8 v = *reinterpret_cast<const u16x8*>(&ob[orow * 136 + och + t * 8]);
      *reinterpret_cast<u16x8*>(og + t * 8) = v;
    }
  }
#undef KFRAG
#undef VFRAG
}

// ---------------- launch ----------------
extern "C" void kernel_launch(void* const* d_in, const int* in_sizes, int n_in,
                              void* d_out, int out_size, void* d_ws, size_t ws_size,
                              hipStream_t stream) {
  (void)in_sizes; (void)n_in; (void)out_size;
  const float* x  = (const float*)d_in[0];
  const float* Wq = (const float*)d_in[1];
  const float* Wk = (const float*)d_in[2];
  const float* Wv = (const float*)d_in[3];
  const float* Wo = (const float*)d_in[4];

  if (ws_size < (size_t)(8388608 + 6291456 + 12582912) * 2) return;
  u16* xb  = (u16*)d_ws;
  u16* Wc  = xb + 8388608;
  u16* QKV = Wc + 6291456;
  u16* Ob  = xb;  // reuse x-bf16 region for attention output

  cvt4_kernel<<<2048, 256, 0, stream>>>(x, Wq, Wk, Wv, xb, Wc);
  gemm_bt<true><<<dim3(24, 32), 256, 0, stream>>>(xb, Wc, (void*)QKV, 4096, 3072, 2048);
  cvt_kernel<<<2048, 256, 0, stream>>>(Wo, Wc, 1048576);
  attn_kernel<<<dim3(256), 256, 0, stream>>>(QKV, Ob);
  gemm_bt<false><<<dim3(16, 32), 256, 0, stream>>>(Ob, Wc, d_out, 4096, 2048, 2048);
}

// Round 9
// 256.835 us; speedup vs baseline: 1.4575x; 1.4575x over previous
//
#include <hip/hip_runtime.h>
#include <hip/hip_bf16.h>
#include <cstdint>
#include <cstddef>

using u16 = unsigned short;
typedef __bf16 bf16x8 __attribute__((ext_vector_type(8)));
typedef float f32x4 __attribute__((ext_vector_type(4)));
typedef float f32x16 __attribute__((ext_vector_type(16)));
typedef u16 u16x4 __attribute__((ext_vector_type(4)));
typedef u16 u16x8 __attribute__((ext_vector_type(8)));
typedef uint32_t u32x4 __attribute__((ext_vector_type(4)));

__device__ __forceinline__ u16 f2bf(float f) {
  uint32_t u = __builtin_bit_cast(uint32_t, f);
  u += 0x7FFFu + ((u >> 16) & 1u);   // RNE
  return (u16)(u >> 16);
}

__device__ __forceinline__ void gld_lds16(const void* g, void* l) {
  __builtin_amdgcn_global_load_lds(
      (const __attribute__((address_space(1))) unsigned int*)g,
      (__attribute__((address_space(3))) unsigned int*)l, 16, 0, 0);
}

#define MFMA16(a, b, c) __builtin_amdgcn_mfma_f32_16x16x32_bf16((a), (b), (c), 0, 0, 0)
#define MFMA32(a, b, c) __builtin_amdgcn_mfma_f32_32x32x16_bf16((a), (b), (c), 0, 0, 0)

__device__ __forceinline__ uint32_t pkbf(float a, float b) {
  uint32_t d;
  asm("v_cvt_pk_bf16_f32 %0, %1, %2" : "=v"(d) : "v"(a), "v"(b));
  return d;
}
__device__ __forceinline__ void swap32(uint32_t& a, uint32_t& b) {
  asm volatile("v_permlane32_swap_b32 %0, %1" : "+v"(a), "+v"(b));
}

// ---------------- fp32 -> bf16 converts ----------------
__global__ void cvt_kernel(const float* __restrict__ in, u16* __restrict__ out, int n4) {
  int i = blockIdx.x * blockDim.x + threadIdx.x;
  int stride = gridDim.x * blockDim.x;
  for (; i < n4; i += stride) {
    float4 v = reinterpret_cast<const float4*>(in)[i];
    u16x4 o;
    o[0] = f2bf(v.x); o[1] = f2bf(v.y); o[2] = f2bf(v.z); o[3] = f2bf(v.w);
    reinterpret_cast<u16x4*>(out)[i] = o;
  }
}

__global__ void cvt4_kernel(const float* __restrict__ x, const float* __restrict__ Wq,
                            const float* __restrict__ Wk, const float* __restrict__ Wv,
                            u16* __restrict__ xb, u16* __restrict__ Wc) {
  int i = blockIdx.x * blockDim.x + threadIdx.x;
  int stride = gridDim.x * blockDim.x;
  for (; i < 3670016; i += stride) {
    const float* src; u16* dst; int off;
    if (i < 2097152)      { src = x;  dst = xb;            off = i; }
    else if (i < 3145728) { src = Wq; dst = Wc;            off = i - 2097152; }
    else if (i < 3407872) { src = Wk; dst = Wc + 4194304;  off = i - 3145728; }
    else                  { src = Wv; dst = Wc + 5242880;  off = i - 3407872; }
    float4 v = reinterpret_cast<const float4*>(src)[off];
    u16x4 o;
    o[0] = f2bf(v.x); o[1] = f2bf(v.y); o[2] = f2bf(v.z); o[3] = f2bf(v.w);
    reinterpret_cast<u16x4*>(dst)[off] = o;
  }
}

// ---------------- bf16 GEMM: C[M,N] = A[M,K] @ B[N,K]^T ----------------
// 128x128 tile, triple-buffered counted-vmcnt pipeline (R5), inner core moved
// to 32x32x16 MFMA: 8 MFMA + 8 b128 frag-reads per wave-K-step (was 16+16).
// Frag reads conflict-free via slot^(row&3) swizzle (pre-swizzled global src,
// XOR'd read; rule #21 pair). C/D layout: col=lane&31, row=(r&3)+8(r>>2)+4*hi.
template <bool OUT_BF16>
__global__ __launch_bounds__(256) void gemm_bt(const u16* __restrict__ A,
                                               const u16* __restrict__ B,
                                               void* __restrict__ Cv,
                                               int M, int N, int K) {
  __shared__ __align__(16) u16 Ash[3][128 * 32];
  __shared__ __align__(16) u16 Bsh[3][128 * 32];
  const int tid = threadIdx.x;
  const int w = tid >> 6, lane = tid & 63;
  const int lq = lane & 31, hi = lane >> 5;
  const int wr = w >> 1, wc = w & 1;
  const int m0 = blockIdx.y * 128, n0 = blockIdx.x * 128;
  // staging: LDS linear (row, slot) <- global (row, slot ^ (row&3));
  // pass rows srow, srow+64: (row&3) identical -> one swizzled col works for both.
  const int srow = w * 16 + (lane >> 2);
  const int sk = ((lane & 3) ^ (srow & 3)) * 8;
  const u16* Abase = A + (size_t)(m0 + srow) * K + sk;
  const u16* Bbase = B + (size_t)(n0 + srow) * K + sk;

  f32x16 acc[2][2];
#pragma unroll
  for (int i = 0; i < 2; i++)
#pragma unroll
    for (int j = 0; j < 2; j++)
#pragma unroll
      for (int r = 0; r < 16; r++) acc[i][j][r] = 0.f;

  auto stage = [&](int bi, int tile) {
    const int kt = tile * 32;
    gld_lds16(Abase + kt,                  &Ash[bi][w * 512]);
    gld_lds16(Abase + (size_t)64 * K + kt, &Ash[bi][2048 + w * 512]);
    gld_lds16(Bbase + kt,                  &Bsh[bi][w * 512]);
    gld_lds16(Bbase + (size_t)64 * K + kt, &Bsh[bi][2048 + w * 512]);
  };

  // frag read: row = (wr|wc)*64 + I*32 + lq; slot = (T*2+hi) ^ (row&3) = ^ (lq&3)
#define AFRAG(BUF, I, T) \
  (*reinterpret_cast<const bf16x8*>(&Ash[BUF][(wr * 64 + (I) * 32 + lq) * 32 + ((((T) * 2 + hi) ^ (lq & 3)) * 8)]))
#define BFRAG(BUF, J, T) \
  (*reinterpret_cast<const bf16x8*>(&Bsh[BUF][(wc * 64 + (J) * 32 + lq) * 32 + ((((T) * 2 + hi) ^ (lq & 3)) * 8)]))

  const int nt = K >> 5;
  stage(0, 0);
  stage(1, 1);
  asm volatile("s_waitcnt vmcnt(4)" ::: "memory");
  __builtin_amdgcn_sched_barrier(0);
  __builtin_amdgcn_s_barrier();
  __builtin_amdgcn_sched_barrier(0);

  int cur = 0;
  for (int t = 0; t < nt; ++t) {
    if (t + 2 < nt) {
      int stg = cur + 2; if (stg >= 3) stg -= 3;
      stage(stg, t + 2);
    }
    bf16x8 af[2][2], bfv[2][2];
#pragma unroll
    for (int i = 0; i < 2; i++)
#pragma unroll
      for (int kk = 0; kk < 2; kk++) {
        af[i][kk]  = AFRAG(cur, i, kk);
        bfv[i][kk] = BFRAG(cur, i, kk);
      }
    __builtin_amdgcn_s_setprio(1);
#pragma unroll
    for (int i = 0; i < 2; i++)
#pragma unroll
      for (int j = 0; j < 2; j++)
#pragma unroll
        for (int kk = 0; kk < 2; kk++)
          acc[i][j] = MFMA32(af[i][kk], bfv[j][kk], acc[i][j]);
    __builtin_amdgcn_s_setprio(0);
    if (t + 1 < nt) {
      if (t + 2 < nt) {
        asm volatile("s_waitcnt vmcnt(4)" ::: "memory");
      } else {
        asm volatile("s_waitcnt vmcnt(0)" ::: "memory");
      }
      __builtin_amdgcn_sched_barrier(0);
      __builtin_amdgcn_s_barrier();
      __builtin_amdgcn_sched_barrier(0);
    }
    cur = (cur == 2) ? 0 : cur + 1;
  }

#pragma unroll
  for (int i = 0; i < 2; i++)
#pragma unroll
    for (int j = 0; j < 2; j++)
#pragma unroll
      for (int r = 0; r < 16; r++) {
        const int row = m0 + wr * 64 + i * 32 + (r & 3) + 8 * (r >> 2) + 4 * hi;
        const int col = n0 + wc * 64 + j * 32 + lq;
        if constexpr (OUT_BF16)
          ((u16*)Cv)[(size_t)row * N + col] = f2bf(acc[i][j][r]);
        else
          ((float*)Cv)[(size_t)row * N + col] = acc[i][j][r];
      }
#undef AFRAG
#undef BFRAG
}

// ---------------- flash attention v5b (R7 verbatim — known-good 113 us) ----------------
__global__ __launch_bounds__(256, 2) void attn_kernel(const u16* __restrict__ QKV,
                                                      u16* __restrict__ O) {
  __shared__ __align__(16) u16 Kb[2][64 * 128];      // [s][128k], 16B-slot ^= (s&7)
  __shared__ __align__(16) u16 Vb[3][2][128 * 32];   // 3 bufs: chunk=s>>5: V^T [d][32s]
  const int tid = threadIdx.x, w = tid >> 6, lane = tid & 63;
  const int lq = lane & 31, hi = lane >> 5;
  const int bid = blockIdx.x;
  const int swz = (bid & 7) * 64 + (bid >> 3);
  const int qt = swz & 15;
  const int bh = swz >> 4;
  const int b = bh >> 4, h = bh & 15, hkv = h >> 2;
  const size_t rowb = (size_t)b * 2048;
  const int qbase = qt * 128 + w * 32;

  const u16* Kg = QKV + 2048 + hkv * 128;
  const u16* Vg = QKV + 2560 + hkv * 128;

  bf16x8 bq[8];
  {
    const u16* qp = QKV + (rowb + qbase + lq) * 3072 + h * 128 + hi * 8;
#pragma unroll
    for (int s5 = 0; s5 < 8; s5++)
      bq[s5] = *reinterpret_cast<const bf16x8*>(qp + s5 * 16);
  }

  const int dg = tid & 7, sl = tid >> 3;

  f32x16 oacc[4], lacc;
#pragma unroll
  for (int dt = 0; dt < 4; dt++)
#pragma unroll
    for (int i = 0; i < 16; i++) oacc[dt][i] = 0.f;
#pragma unroll
  for (int i = 0; i < 16; i++) lacc[i] = 0.f;
  float m = -INFINITY;
  const float CEXP = 0.08838834764831845f * 1.4426950408889634f;  // scale*log2e

  const bf16x8 ones = __builtin_bit_cast(bf16x8,
      u32x4{0x3F803F80u, 0x3F803F80u, 0x3F803F80u, 0x3F803F80u});

  auto stageK = [&](int pb2, int sbase) {
#pragma unroll
    for (int p = 0; p < 4; p++) {
      const int L = p * 2048 + tid * 8;
      const int s = L >> 7;
      const int gI = (L >> 3) & 15;
      gld_lds16(Kg + (rowb + sbase + s) * 3072 + ((gI ^ (s & 7)) << 3),
                &Kb[pb2][p * 2048 + w * 512]);
    }
  };
  auto writeV = [&](int vb3, const u16x8& a00, const u16x8& a01,
                    const u16x8& a10, const u16x8& a11) {
#pragma unroll
    for (int sh2 = 0; sh2 < 2; sh2++)
#pragma unroll
      for (int hf = 0; hf < 2; hf++) {
        const u16x8 v = sh2 ? (hf ? a11 : a10) : (hf ? a01 : a00);
#pragma unroll
        for (int j = 0; j < 8; j++) {
          const int d = dg * 16 + hf * 8 + j;
          const int key = ((d >> 1) ^ (d >> 4)) & 3;
          Vb[vb3][sh2][d * 32 + (sl ^ (key << 3))] = v[j];
        }
      }
  };

#define KFRAG(PB, SH, S5) \
  (*reinterpret_cast<const bf16x8*>(&Kb[PB][((SH)*32 + lq) * 128 + ((((S5)*2 + hi) ^ (lq & 7)) << 3)]))
#define VFRAG(VB, DT, SS) \
  (*reinterpret_cast<const bf16x8*>(&Vb[VB][(SS) >> 1][((DT)*32 + lq) * 32 + \
      ((((SS) & 1) * 16 + hi * 8) ^ (((((DT)*32 + lq) >> 1) ^ (((DT)*32 + lq) >> 4)) & 3) << 3)]))

  u16x8 v00, v01, v10, v11;
  {
    const u16* vp = Vg + (rowb + sl) * 3072 + dg * 16;
    v00 = *reinterpret_cast<const u16x8*>(vp);
    v01 = *reinterpret_cast<const u16x8*>(vp + 8);
    const u16* vp2 = vp + (size_t)32 * 3072;
    v10 = *reinterpret_cast<const u16x8*>(vp2);
    v11 = *reinterpret_cast<const u16x8*>(vp2 + 8);
  }
  stageK(0, 0);
  writeV(0, v00, v01, v10, v11);
  __syncthreads();

  bf16x8 pf0, pf1, pf2, pf3;   // P frags of PREVIOUS tile during iteration body
  int vprev = 2, vcur = 0, vnext = 1;

#pragma unroll 1
  for (int sb = 0; sb < 32; sb++) {
    const int pb = sb & 1;
    if (sb < 31) {
      const u16* vp = Vg + (rowb + (sb + 1) * 64 + sl) * 3072 + dg * 16;
      v00 = *reinterpret_cast<const u16x8*>(vp);
      v01 = *reinterpret_cast<const u16x8*>(vp + 8);
      const u16* vp2 = vp + (size_t)32 * 3072;
      v10 = *reinterpret_cast<const u16x8*>(vp2);
      v11 = *reinterpret_cast<const u16x8*>(vp2 + 8);
      stageK(pb ^ 1, (sb + 1) * 64);
    }

    f32x16 sc0, sc1;
#pragma unroll
    for (int i = 0; i < 16; i++) { sc0[i] = 0.f; sc1[i] = 0.f; }
    __builtin_amdgcn_s_setprio(1);
#pragma unroll
    for (int s5 = 0; s5 < 8; s5++) {
      sc0 = MFMA32(KFRAG(pb, 0, s5), bq[s5], sc0);
      sc1 = MFMA32(KFRAG(pb, 1, s5), bq[s5], sc1);
    }
    __builtin_amdgcn_s_setprio(0);

    if (sb) {
      __builtin_amdgcn_s_setprio(1);
#pragma unroll
      for (int dt = 0; dt < 4; dt++) {
        oacc[dt] = MFMA32(VFRAG(vprev, dt, 0), pf0, oacc[dt]);
        oacc[dt] = MFMA32(VFRAG(vprev, dt, 1), pf1, oacc[dt]);
        oacc[dt] = MFMA32(VFRAG(vprev, dt, 2), pf2, oacc[dt]);
        oacc[dt] = MFMA32(VFRAG(vprev, dt, 3), pf3, oacc[dt]);
      }
      __builtin_amdgcn_s_setprio(0);
    }

    float u[16];
#pragma unroll
    for (int i = 0; i < 16; i++) u[i] = fmaxf(sc0[i], sc1[i]);
#pragma unroll
    for (int i = 0; i < 8; i++) u[i] = fmaxf(u[i], u[i + 8]);
#pragma unroll
    for (int i = 0; i < 4; i++) u[i] = fmaxf(u[i], u[i + 4]);
    float mx = fmaxf(fmaxf(u[0], u[1]), fmaxf(u[2], u[3]));
    mx = fmaxf(mx, __shfl_xor(mx, 32));

    if (__any((mx - m) * CEXP > 8.0f)) {
      const float mn = fmaxf(m, mx);
      const float corr = exp2f((m - mn) * CEXP);
#pragma unroll
      for (int i = 0; i < 16; i++) lacc[i] *= corr;
#pragma unroll
      for (int dt = 0; dt < 4; dt++)
#pragma unroll
        for (int i = 0; i < 16; i++) oacc[dt][i] *= corr;
      m = mn;
    }

    const float mC = m * CEXP;
    float e0[16], e1[16];
#pragma unroll
    for (int i = 0; i < 16; i++) {
      e0[i] = exp2f(fmaf(sc0[i], CEXP, -mC));
      e1[i] = exp2f(fmaf(sc1[i], CEXP, -mC));
    }
    {
      uint32_t a, bw;
      u32x4 f;
      a = pkbf(e0[0], e0[1]);  bw = pkbf(e0[4], e0[5]);  swap32(a, bw);
      f[0] = a; f[2] = bw;
      a = pkbf(e0[2], e0[3]);  bw = pkbf(e0[6], e0[7]);  swap32(a, bw);
      f[1] = a; f[3] = bw;
      pf0 = __builtin_bit_cast(bf16x8, f);
      a = pkbf(e0[8], e0[9]);  bw = pkbf(e0[12], e0[13]); swap32(a, bw);
      f[0] = a; f[2] = bw;
      a = pkbf(e0[10], e0[11]); bw = pkbf(e0[14], e0[15]); swap32(a, bw);
      f[1] = a; f[3] = bw;
      pf1 = __builtin_bit_cast(bf16x8, f);
      a = pkbf(e1[0], e1[1]);  bw = pkbf(e1[4], e1[5]);  swap32(a, bw);
      f[0] = a; f[2] = bw;
      a = pkbf(e1[2], e1[3]);  bw = pkbf(e1[6], e1[7]);  swap32(a, bw);
      f[1] = a; f[3] = bw;
      pf2 = __builtin_bit_cast(bf16x8, f);
      a = pkbf(e1[8], e1[9]);  bw = pkbf(e1[12], e1[13]); swap32(a, bw);
      f[0] = a; f[2] = bw;
      a = pkbf(e1[10], e1[11]); bw = pkbf(e1[14], e1[15]); swap32(a, bw);
      f[1] = a; f[3] = bw;
      pf3 = __builtin_bit_cast(bf16x8, f);
    }

    lacc = MFMA32(ones, pf0, lacc);
    lacc = MFMA32(ones, pf1, lacc);
    lacc = MFMA32(ones, pf2, lacc);
    lacc = MFMA32(ones, pf3, lacc);

    if (sb < 31) writeV(vnext, v00, v01, v10, v11);
    __syncthreads();

    const int tmp = vprev; vprev = vcur; vcur = vnext; vnext = tmp;
  }

  {
    __builtin_amdgcn_s_setprio(1);
#pragma unroll
    for (int dt = 0; dt < 4; dt++) {
      oacc[dt] = MFMA32(VFRAG(vprev, dt, 0), pf0, oacc[dt]);
      oacc[dt] = MFMA32(VFRAG(vprev, dt, 1), pf1, oacc[dt]);
      oacc[dt] = MFMA32(VFRAG(vprev, dt, 2), pf2, oacc[dt]);
      oacc[dt] = MFMA32(VFRAG(vprev, dt, 3), pf3, oacc[dt]);
    }
    __builtin_amdgcn_s_setprio(0);
  }
  __syncthreads();

  const float rl = 1.0f / lacc[0];
  u16* ob = (w < 2) ? &Kb[w][0] : &Vb[w - 2][0][0];
#pragma unroll
  for (int dt = 0; dt < 4; dt++)
#pragma unroll
    for (int rq = 0; rq < 4; rq++) {
      u16x4 pv;
#pragma unroll
      for (int k = 0; k < 4; k++) pv[k] = f2bf(oacc[dt][rq * 4 + k] * rl);
      *reinterpret_cast<u16x4*>(&ob[lq * 136 + dt * 32 + rq * 8 + hi * 4]) = pv;
    }
  const int orow = lane >> 1, och = (lane & 1) * 64;
  u16* og = O + (rowb + qbase + orow) * 2048 + h * 128 + och;
#pragma unroll
  for (int t = 0; t < 8; t++) {
    u16x8 v = *reinterpret_cast<const u16x8*>(&ob[orow * 136 + och + t * 8]);
    *reinterpret_cast<u16x8*>(og + t * 8) = v;
  }
#undef KFRAG
#undef VFRAG
}

// ---------------- launch ----------------
extern "C" void kernel_launch(void* const* d_in, const int* in_sizes, int n_in,
                              void* d_out, int out_size, void* d_ws, size_t ws_size,
                              hipStream_t stream) {
  (void)in_sizes; (void)n_in; (void)out_size;
  const float* x  = (const float*)d_in[0];
  const float* Wq = (const float*)d_in[1];
  const float* Wk = (const float*)d_in[2];
  const float* Wv = (const float*)d_in[3];
  const float* Wo = (const float*)d_in[4];

  if (ws_size < (size_t)(8388608 + 6291456 + 12582912) * 2) return;
  u16* xb  = (u16*)d_ws;
  u16* Wc  = xb + 8388608;
  u16* QKV = Wc + 6291456;
  u16* Ob  = xb;  // reuse x-bf16 region for attention output

  cvt4_kernel<<<2048, 256, 0, stream>>>(x, Wq, Wk, Wv, xb, Wc);
  gemm_bt<true><<<dim3(24, 32), 256, 0, stream>>>(xb, Wc, (void*)QKV, 4096, 3072, 2048);
  cvt_kernel<<<2048, 256, 0, stream>>>(Wo, Wc, 1048576);
  attn_kernel<<<dim3(512), 256, 0, stream>>>(QKV, Ob);
  gemm_bt<false><<<dim3(16, 32), 256, 0, stream>>>(Ob, Wc, d_out, 4096, 2048, 2048);
}